// Round 1
// baseline (842.054 us; speedup 1.0000x reference)
//
#include <hip/hip_runtime.h>
#include <math.h>

#define NB 32
#define ND 768
#define NS 196
#define NL 77
#define BUFW 80
#define CTW 200
#define CTTW 260

// ws layout (floats):
// n1ws   : [0, 2560)       word norms [32][80]
// simws  : [2560, 3584)    sim[i][j]  [32][32]
// gscw   : [3584, 4608)    global scores [32][32]
// invni  : [4608, 4640)
// invnt  : [4640, 4672)
// lenws  : ints at [4672, 4704)

// -------------------- prep: caption lengths, word norms, global norms --------------------
__global__ void prep_kernel(const float* __restrict__ img_global,
                            const float* __restrict__ text_global,
                            const float* __restrict__ text_local,
                            const int* __restrict__ amask,
                            float* __restrict__ n1ws, int* __restrict__ lenws,
                            float* __restrict__ invni, float* __restrict__ invnt) {
  const int i = blockIdx.x;
  const int t = threadIdx.x;
  const int lane = t & 63;
  const int w = t >> 6;
  __shared__ int slen;
  if (t == 0) slen = 0;
  __syncthreads();
  if (t < NL && amask[i * NL + t] != 0) atomicAdd(&slen, 1);

  // n1[i][l] = ||text_local[i,l,:]||
  for (int l = w; l < NL; l += 4) {
    const float4* p = (const float4*)(text_local + ((size_t)i * NL + l) * ND);
    float s = 0.f;
#pragma unroll
    for (int k = 0; k < 3; ++k) {
      float4 v = p[lane + 64 * k];
      s += v.x * v.x + v.y * v.y + v.z * v.z + v.w * v.w;
    }
#pragma unroll
    for (int off = 32; off; off >>= 1) s += __shfl_xor(s, off);
    if (lane == 0) n1ws[i * BUFW + l] = sqrtf(s);
  }
  // global-vector inverse norms
  if (w < 2) {
    const float* src = (w == 0) ? img_global : text_global;
    const float4* p = (const float4*)(src + (size_t)i * ND);
    float s = 0.f;
#pragma unroll
    for (int k = 0; k < 3; ++k) {
      float4 v = p[lane + 64 * k];
      s += v.x * v.x + v.y * v.y + v.z * v.z + v.w * v.w;
    }
#pragma unroll
    for (int off = 32; off; off >>= 1) s += __shfl_xor(s, off);
    if (lane == 0) {
      float inv = 1.0f / fmaxf(sqrtf(s), 1e-12f);
      if (w == 0) invni[i] = inv; else invnt[i] = inv;
    }
  }
  __syncthreads();
  if (t == 0) lenws[i] = slen;
}

// -------------------- global contrastive scores --------------------
__global__ void gsc_kernel(const float* __restrict__ img_global,
                           const float* __restrict__ text_global,
                           const float* __restrict__ invni,
                           const float* __restrict__ invnt,
                           float* __restrict__ gscw) {
  const int a = blockIdx.x;
  const int t = threadIdx.x;
  const int lane = t & 63;
  const int w = t >> 6;
  __shared__ __align__(16) float shi[ND];
  if (t < ND / 4) ((float4*)shi)[t] = ((const float4*)(img_global + (size_t)a * ND))[t];
  __syncthreads();
  for (int b = w; b < NB; b += 4) {
    const float4* pt = (const float4*)(text_global + (size_t)b * ND);
    const float4* pi = (const float4*)shi;
    float s = 0.f;
#pragma unroll
    for (int k = 0; k < 3; ++k) {
      float4 x = pi[lane + 64 * k];
      float4 y = pt[lane + 64 * k];
      s += x.x * y.x + x.y * y.y + x.z * y.z + x.w * y.w;
    }
#pragma unroll
    for (int off = 32; off; off >>= 1) s += __shfl_xor(s, off);
    if (lane == 0) gscw[a * NB + b] = s * invni[a] * invnt[b] * 10.0f;
  }
}

// -------------------- per-pair fused local loss --------------------
__global__ __launch_bounds__(256, 2) void pair_kernel(
    const float* __restrict__ img_local,
    const float* __restrict__ text_local,
    const float* __restrict__ n1ws,
    const int* __restrict__ lenws,
    float* __restrict__ simws) {
  const int t = threadIdx.x;
  const int bid = blockIdx.x;
  const int i = bid >> 5;  // text index
  const int j = bid & 31;  // image index
  const int len = lenws[i];

  __shared__ __align__(16) float Buf[NS * BUFW];   // 62720 B: logits then e2, [s][l]
  __shared__ __align__(16) float Stage[4480];      // 17920 B staging union
  __shared__ float w12s[BUFW];
  __shared__ float n2s[BUFW];
  __shared__ float z2invs[BUFW];

  float* ctx_tile = Stage;             // [16][CTW]
  float* tl_tile  = Stage + 16 * CTW;  // [16][BUFW]

  const float* ctxg = img_local + (size_t)j * ND * NS;   // [d][s]
  const float* tlg  = text_local + (size_t)i * NL * ND;  // [l][d]

  // zero-init Buf + accumulators
  for (int idx = t; idx < NS * BUFW / 4; idx += 256)
    ((float4*)Buf)[idx] = make_float4(0.f, 0.f, 0.f, 0.f);
  if (t < BUFW) { w12s[t] = 0.f; n2s[t] = 0.f; }

  // ========== GEMM1: Buf[s][l] = sum_d ctx[d][s] * tl[l][d] ==========
  {
    const int st = t & 31;
    const int lt = t >> 5;
    const int s0 = st * 8;
    const int l0 = lt * 8;
    const int ltail = 64 + lt * 2;
    const bool act = (st < 25);
    const bool doM = act && (l0 < len);
    const bool doT = act && (len > 64);

    float accM[8][8];
    float accT[8][2];
#pragma unroll
    for (int a = 0; a < 8; ++a) {
      accT[a][0] = 0.f; accT[a][1] = 0.f;
#pragma unroll
      for (int b = 0; b < 8; ++b) accM[a][b] = 0.f;
    }

    for (int dk = 0; dk < ND; dk += 16) {
      __syncthreads();
      // stage ctx tile [16][200] (cols 196..199 zero)
      for (int idx = t; idx < 800; idx += 256) {
        int dd = idx / 50;
        int q = idx - dd * 50;
        float4 v = make_float4(0.f, 0.f, 0.f, 0.f);
        if (q < 49) v = *(const float4*)(ctxg + (size_t)(dk + dd) * NS + q * 4);
        *(float4*)(ctx_tile + dd * CTW + q * 4) = v;
      }
      // stage tl tile [16][80] transposed (l >= 77 zero)
      for (int idx = t; idx < 320; idx += 256) {
        int l = idx >> 2;
        int dq = idx & 3;
        float4 v = make_float4(0.f, 0.f, 0.f, 0.f);
        if (l < NL) v = *(const float4*)(tlg + (size_t)l * ND + dk + dq * 4);
        tl_tile[(dq * 4 + 0) * BUFW + l] = v.x;
        tl_tile[(dq * 4 + 1) * BUFW + l] = v.y;
        tl_tile[(dq * 4 + 2) * BUFW + l] = v.z;
        tl_tile[(dq * 4 + 3) * BUFW + l] = v.w;
      }
      __syncthreads();
      if (doM || doT) {
#pragma unroll 4
        for (int dd = 0; dd < 16; ++dd) {
          float4 a0 = *(const float4*)(ctx_tile + dd * CTW + s0);
          float4 a1 = *(const float4*)(ctx_tile + dd * CTW + s0 + 4);
          float Ar[8] = {a0.x, a0.y, a0.z, a0.w, a1.x, a1.y, a1.z, a1.w};
          if (doM) {
            float4 b0 = *(const float4*)(tl_tile + dd * BUFW + l0);
            float4 b1 = *(const float4*)(tl_tile + dd * BUFW + l0 + 4);
            float Br[8] = {b0.x, b0.y, b0.z, b0.w, b1.x, b1.y, b1.z, b1.w};
#pragma unroll
            for (int a = 0; a < 8; ++a)
#pragma unroll
              for (int b = 0; b < 8; ++b)
                accM[a][b] = fmaf(Ar[a], Br[b], accM[a][b]);
          }
          if (doT) {
            float bt0 = tl_tile[dd * BUFW + ltail];
            float bt1 = tl_tile[dd * BUFW + ltail + 1];
#pragma unroll
            for (int a = 0; a < 8; ++a) {
              accT[a][0] = fmaf(Ar[a], bt0, accT[a][0]);
              accT[a][1] = fmaf(Ar[a], bt1, accT[a][1]);
            }
          }
        }
      }
    }
    // write logits
#pragma unroll
    for (int a = 0; a < 8; ++a) {
      int s = s0 + a;
      if (s < NS) {
        if (doM) {
          *(float4*)(Buf + s * BUFW + l0) =
              make_float4(accM[a][0], accM[a][1], accM[a][2], accM[a][3]);
          *(float4*)(Buf + s * BUFW + l0 + 4) =
              make_float4(accM[a][4], accM[a][5], accM[a][6], accM[a][7]);
        }
        if (doT) {
          Buf[s * BUFW + ltail] = accT[a][0];
          Buf[s * BUFW + ltail + 1] = accT[a][1];
        }
      }
    }
  }
  __syncthreads();

  // ========== softmax over l (per s), then Buf = exp(4 * a1) ==========
  {
    const int lane = t & 63;
    const int w = t >> 6;
    for (int s = w; s < NS; s += 4) {
      float v0 = (lane < len) ? Buf[s * BUFW + lane] : -1e30f;
      float v1 = (lane + 64 < len) ? Buf[s * BUFW + lane + 64] : -1e30f;
      float m = fmaxf(v0, v1);
#pragma unroll
      for (int off = 32; off; off >>= 1) m = fmaxf(m, __shfl_xor(m, off));
      float e0 = __expf(v0 - m);
      float e1 = __expf(v1 - m);
      float z = e0 + e1;
#pragma unroll
      for (int off = 32; off; off >>= 1) z += __shfl_xor(z, off);
      float inv4 = 4.0f / z;
      if (lane < len) Buf[s * BUFW + lane] = __expf(e0 * inv4);
      if (lane + 64 < len) Buf[s * BUFW + lane + 64] = __expf(e1 * inv4);
    }
  }
  __syncthreads();

  // ========== Z2[l] = sum_s e2[s][l] ==========
  if (t < len) {
    float z2 = 0.f;
    for (int s = 0; s < NS; ++s) z2 += Buf[s * BUFW + t];
    z2invs[t] = 1.0f / z2;
  }
  __syncthreads();

  // ========== GEMM2: raw_wc[d][l] = sum_s ctx[d][s]*e2[s][l]; fold into w12/n2 ==========
  {
    const int dth = t & 31;
    const int lth = t >> 5;
    const int lb0 = lth * 8;
    const int ltail = 64 + lth * 2;
    const bool doM = (lb0 < len);
    const bool doT = (len > 64);
    float* ctxT = Stage;  // [16][CTTW]

    for (int pass = 0; pass < 3; ++pass) {
      const int dbase = pass * 256;
      float acc[8][8];
      float acc2[8][2];
#pragma unroll
      for (int a = 0; a < 8; ++a) {
        acc2[a][0] = 0.f; acc2[a][1] = 0.f;
#pragma unroll
        for (int b = 0; b < 8; ++b) acc[a][b] = 0.f;
      }
      for (int sc = 0; sc < 13; ++sc) {
        __syncthreads();
#pragma unroll
        for (int k = 0; k < 4; ++k) {
          int idx = t + k * 256;
          int dloc = idx >> 2;
          int sq = idx & 3;
          int sbase = sc * 16 + sq * 4;
          float4 v = make_float4(0.f, 0.f, 0.f, 0.f);
          if (sbase < NS) v = *(const float4*)(ctxg + (size_t)(dbase + dloc) * NS + sbase);
          ctxT[(sq * 4 + 0) * CTTW + dloc] = v.x;
          ctxT[(sq * 4 + 1) * CTTW + dloc] = v.y;
          ctxT[(sq * 4 + 2) * CTTW + dloc] = v.z;
          ctxT[(sq * 4 + 3) * CTTW + dloc] = v.w;
        }
        __syncthreads();
        if (doM || doT) {
          const int ns = (sc == 12) ? 4 : 16;
          for (int ss = 0; ss < ns; ++ss) {
            const int s = sc * 16 + ss;
            float4 a0 = *(const float4*)(ctxT + ss * CTTW + dth * 8);
            float4 a1 = *(const float4*)(ctxT + ss * CTTW + dth * 8 + 4);
            float Ar[8] = {a0.x, a0.y, a0.z, a0.w, a1.x, a1.y, a1.z, a1.w};
            if (doM) {
              float4 b0 = *(const float4*)(Buf + s * BUFW + lb0);
              float4 b1 = *(const float4*)(Buf + s * BUFW + lb0 + 4);
              float Br[8] = {b0.x, b0.y, b0.z, b0.w, b1.x, b1.y, b1.z, b1.w};
#pragma unroll
              for (int a = 0; a < 8; ++a)
#pragma unroll
                for (int b = 0; b < 8; ++b)
                  acc[a][b] = fmaf(Ar[a], Br[b], acc[a][b]);
            }
            if (doT) {
              float bt0 = Buf[s * BUFW + ltail];
              float bt1 = Buf[s * BUFW + ltail + 1];
#pragma unroll
              for (int a = 0; a < 8; ++a) {
                acc2[a][0] = fmaf(Ar[a], bt0, acc2[a][0]);
                acc2[a][1] = fmaf(Ar[a], bt1, acc2[a][1]);
              }
            }
          }
        }
      }
      // epilogue: partial w12 / n2 over this pass's 8 d's
      float pw[10], pn[10];
#pragma unroll
      for (int v = 0; v < 10; ++v) { pw[v] = 0.f; pn[v] = 0.f; }
      const int d0 = dbase + dth * 8;
#pragma unroll
      for (int b = 0; b < 8; ++b) {
        int l = lb0 + b;
        if (l < len) {
          const float* tp = tlg + (size_t)l * ND + d0;
          float4 t0 = *(const float4*)tp;
          float4 t1 = *(const float4*)(tp + 4);
          float Tv[8] = {t0.x, t0.y, t0.z, t0.w, t1.x, t1.y, t1.z, t1.w};
          float w_ = 0.f, n_ = 0.f;
#pragma unroll
          for (int a = 0; a < 8; ++a) {
            w_ = fmaf(Tv[a], acc[a][b], w_);
            n_ = fmaf(acc[a][b], acc[a][b], n_);
          }
          pw[b] = w_; pn[b] = n_;
        }
      }
#pragma unroll
      for (int b = 0; b < 2; ++b) {
        int l = ltail + b;
        if (l < len) {
          const float* tp = tlg + (size_t)l * ND + d0;
          float4 t0 = *(const float4*)tp;
          float4 t1 = *(const float4*)(tp + 4);
          float Tv[8] = {t0.x, t0.y, t0.z, t0.w, t1.x, t1.y, t1.z, t1.w};
          float w_ = 0.f, n_ = 0.f;
#pragma unroll
          for (int a = 0; a < 8; ++a) {
            w_ = fmaf(Tv[a], acc2[a][b], w_);
            n_ = fmaf(acc2[a][b], acc2[a][b], n_);
          }
          pw[8 + b] = w_; pn[8 + b] = n_;
        }
      }
#pragma unroll
      for (int m = 16; m >= 1; m >>= 1) {
#pragma unroll
        for (int v = 0; v < 10; ++v) {
          pw[v] += __shfl_xor(pw[v], m, 32);
          pn[v] += __shfl_xor(pn[v], m, 32);
        }
      }
      if (dth == 0) {
#pragma unroll
        for (int v = 0; v < 10; ++v) {
          int l = (v < 8) ? (lb0 + v) : (ltail + v - 8);
          if (l < len) {
            atomicAdd(&w12s[l], pw[v]);
            atomicAdd(&n2s[l], pn[v]);
          }
        }
      }
    }
  }
  __syncthreads();

  // ========== cosine + log-sum-exp(5*cos) ==========
  if (t < len) {
    float w12v = w12s[t] * z2invs[t];
    float n2v = sqrtf(n2s[t]) * z2invs[t];
    float n1v = n1ws[i * BUFW + t];
    float cosv = w12v / fmaxf(n1v * n2v, 1e-8f);
    w12s[t] = __expf(5.0f * cosv);
  }
  __syncthreads();
  if (t == 0) {
    float sum = 0.f;
    for (int l = 0; l < len; ++l) sum += w12s[l];
    simws[i * NB + j] = __logf(sum);
  }
}

// -------------------- final cross-entropies --------------------
__global__ void loss_kernel(const float* __restrict__ gscw,
                            const float* __restrict__ simws,
                            float* __restrict__ out) {
  const int t = threadIdx.x;
  __shared__ float gs[NB][NB];
  __shared__ float sl[NB][NB];
  __shared__ float parts[4][NB];
  {
    float4 g = ((const float4*)gscw)[t];
    ((float4*)gs)[t] = g;
    float4 v = ((const float4*)simws)[t];
    int ii = t >> 3;
    int j0 = (t & 7) * 4;
    sl[j0 + 0][ii] = v.x * 10.0f;
    sl[j0 + 1][ii] = v.y * 10.0f;
    sl[j0 + 2][ii] = v.z * 10.0f;
    sl[j0 + 3][ii] = v.w * 10.0f;
  }
  __syncthreads();
  if (t < NB) {
    float m, z;
    m = -1e30f;
    for (int c = 0; c < NB; ++c) m = fmaxf(m, gs[t][c]);
    z = 0.f;
    for (int c = 0; c < NB; ++c) z += __expf(gs[t][c] - m);
    parts[0][t] = m + __logf(z) - gs[t][t];

    m = -1e30f;
    for (int c = 0; c < NB; ++c) m = fmaxf(m, gs[c][t]);
    z = 0.f;
    for (int c = 0; c < NB; ++c) z += __expf(gs[c][t] - m);
    parts[1][t] = m + __logf(z) - gs[t][t];

    m = -1e30f;
    for (int c = 0; c < NB; ++c) m = fmaxf(m, sl[t][c]);
    z = 0.f;
    for (int c = 0; c < NB; ++c) z += __expf(sl[t][c] - m);
    parts[2][t] = m + __logf(z) - sl[t][t];

    m = -1e30f;
    for (int c = 0; c < NB; ++c) m = fmaxf(m, sl[c][t]);
    z = 0.f;
    for (int c = 0; c < NB; ++c) z += __expf(sl[c][t] - m);
    parts[3][t] = m + __logf(z) - sl[t][t];
  }
  __syncthreads();
  if (t == 0) {
    float s0 = 0.f, s1 = 0.f, s2 = 0.f, s3 = 0.f;
    for (int r = 0; r < NB; ++r) {
      s0 += parts[0][r]; s1 += parts[1][r];
      s2 += parts[2][r]; s3 += parts[3][r];
    }
    out[0] = 0.5f * (s0 + s1) / 32.0f + 0.5f * (s2 + s3) / 32.0f;
  }
}

extern "C" void kernel_launch(void* const* d_in, const int* in_sizes, int n_in,
                              void* d_out, int out_size, void* d_ws, size_t ws_size,
                              hipStream_t stream) {
  (void)in_sizes; (void)n_in; (void)out_size; (void)ws_size;
  const float* img_global  = (const float*)d_in[0];
  const float* img_local   = (const float*)d_in[1];
  const float* text_global = (const float*)d_in[2];
  const float* text_local  = (const float*)d_in[3];
  const int*   amask       = (const int*)d_in[4];

  float* f = (float*)d_ws;
  float* n1ws  = f;
  float* simws = f + 2560;
  float* gscw  = f + 3584;
  float* invni = f + 4608;
  float* invnt = f + 4640;
  int*   lenws = (int*)(f + 4672);

  prep_kernel<<<32, 256, 0, stream>>>(img_global, text_global, text_local, amask,
                                      n1ws, lenws, invni, invnt);
  gsc_kernel<<<32, 256, 0, stream>>>(img_global, text_global, invni, invnt, gscw);
  pair_kernel<<<1024, 256, 0, stream>>>(img_local, text_local, n1ws, lenws, simws);
  loss_kernel<<<1, 256, 0, stream>>>(gscw, simws, (float*)d_out);
}

// Round 2
// 305.271 us; speedup vs baseline: 2.7584x; 2.7584x over previous
//
#include <hip/hip_runtime.h>
#include <math.h>

#define NB 32
#define ND 768
#define NS 196
#define NL 77

typedef __bf16 bf16x8 __attribute__((ext_vector_type(8)));
typedef float f32x4 __attribute__((ext_vector_type(4)));

__device__ __forceinline__ f32x4 mfma16(bf16x8 a, bf16x8 b, f32x4 c) {
  return __builtin_amdgcn_mfma_f32_16x16x32_bf16(a, b, c, 0, 0, 0);
}

// -------------------- prep: caption lengths, word norms, global norms --------------------
__global__ void prep_kernel(const float* __restrict__ img_global,
                            const float* __restrict__ text_global,
                            const float* __restrict__ text_local,
                            const int* __restrict__ amask,
                            float* __restrict__ n1ws, int* __restrict__ lenws,
                            float* __restrict__ invni, float* __restrict__ invnt) {
  const int i = blockIdx.x;
  const int t = threadIdx.x;
  const int lane = t & 63;
  const int w = t >> 6;
  __shared__ int slen;
  if (t == 0) slen = 0;
  __syncthreads();
  if (t < NL && amask[i * NL + t] != 0) atomicAdd(&slen, 1);

  for (int l = w; l < NL; l += 4) {
    const float4* p = (const float4*)(text_local + ((size_t)i * NL + l) * ND);
    float s = 0.f;
#pragma unroll
    for (int k = 0; k < 3; ++k) {
      float4 v = p[lane + 64 * k];
      s += v.x * v.x + v.y * v.y + v.z * v.z + v.w * v.w;
    }
#pragma unroll
    for (int off = 32; off; off >>= 1) s += __shfl_xor(s, off);
    if (lane == 0) n1ws[i * 80 + l] = sqrtf(s);
  }
  if (w < 2) {
    const float* src = (w == 0) ? img_global : text_global;
    const float4* p = (const float4*)(src + (size_t)i * ND);
    float s = 0.f;
#pragma unroll
    for (int k = 0; k < 3; ++k) {
      float4 v = p[lane + 64 * k];
      s += v.x * v.x + v.y * v.y + v.z * v.z + v.w * v.w;
    }
#pragma unroll
    for (int off = 32; off; off >>= 1) s += __shfl_xor(s, off);
    if (lane == 0) {
      float inv = 1.0f / fmaxf(sqrtf(s), 1e-12f);
      if (w == 0) invni[i] = inv; else invnt[i] = inv;
    }
  }
  __syncthreads();
  if (t == 0) lenws[i] = slen;
}

// -------------------- global contrastive scores --------------------
__global__ void gsc_kernel(const float* __restrict__ img_global,
                           const float* __restrict__ text_global,
                           const float* __restrict__ invni,
                           const float* __restrict__ invnt,
                           float* __restrict__ gscw) {
  const int a = blockIdx.x;
  const int t = threadIdx.x;
  const int lane = t & 63;
  const int w = t >> 6;
  __shared__ __align__(16) float shi[ND];
  if (t < ND / 4) ((float4*)shi)[t] = ((const float4*)(img_global + (size_t)a * ND))[t];
  __syncthreads();
  for (int b = w; b < NB; b += 4) {
    const float4* pt = (const float4*)(text_global + (size_t)b * ND);
    const float4* pi = (const float4*)shi;
    float s = 0.f;
#pragma unroll
    for (int k = 0; k < 3; ++k) {
      float4 x = pi[lane + 64 * k];
      float4 y = pt[lane + 64 * k];
      s += x.x * y.x + x.y * y.y + x.z * y.z + x.w * y.w;
    }
#pragma unroll
    for (int off = 32; off; off >>= 1) s += __shfl_xor(s, off);
    if (lane == 0) gscw[a * NB + b] = s * invni[a] * invnt[b] * 10.0f;
  }
}

// -------------------- text bf16 hi/lo planes (padded to 80 rows) --------------------
__global__ void tx_kernel(const float* __restrict__ text_local,
                          __bf16* __restrict__ txh, __bf16* __restrict__ txl) {
  int tau = blockIdx.x * 256 + threadIdx.x;  // 32*80*96
  int i = tau / 7680;
  int rem = tau - i * 7680;
  int l = rem / 96;
  int o = rem - l * 96;
  float v[8];
#pragma unroll
  for (int q = 0; q < 8; ++q) v[q] = 0.f;
  if (l < NL) {
    const float* src = text_local + ((size_t)i * NL + l) * ND + o * 8;
    float4 a = *(const float4*)src;
    float4 b = *(const float4*)(src + 4);
    v[0] = a.x; v[1] = a.y; v[2] = a.z; v[3] = a.w;
    v[4] = b.x; v[5] = b.y; v[6] = b.z; v[7] = b.w;
  }
  bf16x8 hv, lv;
#pragma unroll
  for (int q = 0; q < 8; ++q) {
    __bf16 h = (__bf16)v[q];
    hv[q] = h;
    lv[q] = (__bf16)(v[q] - (float)h);
  }
  size_t off = ((size_t)i * 80 + l) * ND + o * 8;
  *(bf16x8*)(txh + off) = hv;
  *(bf16x8*)(txl + off) = lv;
}

// -------------------- ctx transpose to [s][d] bf16 hi/lo (padded to 208 rows) --------------------
__global__ void trans_kernel(const float* __restrict__ img_local,
                             __bf16* __restrict__ cTh, __bf16* __restrict__ cTl) {
  const int bid = blockIdx.x;  // 32*12
  const int j = bid / 12, dc = bid - (bid / 12) * 12;
  const int t = threadIdx.x;
  for (int tau = t; tau < 1664; tau += 256) {  // 8 octets * 208 s
    int o = tau / 208, s = tau - (tau / 208) * 208;
    float v[8];
#pragma unroll
    for (int q = 0; q < 8; ++q) v[q] = 0.f;
    if (s < NS) {
#pragma unroll
      for (int q = 0; q < 8; ++q)
        v[q] = img_local[((size_t)j * ND + dc * 64 + o * 8 + q) * NS + s];
    }
    bf16x8 hv, lv;
#pragma unroll
    for (int q = 0; q < 8; ++q) {
      __bf16 h = (__bf16)v[q];
      hv[q] = h;
      lv[q] = (__bf16)(v[q] - (float)h);
    }
    size_t off = ((size_t)j * 208 + s) * ND + dc * 64 + o * 8;
    *(bf16x8*)(cTh + off) = hv;
    *(bf16x8*)(cTl + off) = lv;
  }
}

// -------------------- per-image Gram matrix G = ctx^T ctx, bf16 hi/lo [208][224] --------------------
__global__ void gram_kernel(const __bf16* __restrict__ cTh, const __bf16* __restrict__ cTl,
                            __bf16* __restrict__ Ghp, __bf16* __restrict__ Glp) {
  const int bid = blockIdx.x;  // 32*13
  const int j = bid / 13, st = bid - (bid / 13) * 13;
  const int t = threadIdx.x, lane = t & 63, w = t >> 6;
  const int g = lane >> 4, n16 = lane & 15;
  const size_t cb = (size_t)j * 208;
  const f32x4 z4 = {0.f, 0.f, 0.f, 0.f};
  f32x4 accG[4];
#pragma unroll
  for (int q = 0; q < 4; ++q) accG[q] = z4;
  const size_t aoff = (cb + st * 16 + n16) * ND + g * 8;
  for (int dk = 0; dk < 24; ++dk) {
    bf16x8 Ah = *(const bf16x8*)(cTh + aoff + dk * 32);
    bf16x8 Al = *(const bf16x8*)(cTl + aoff + dk * 32);
#pragma unroll
    for (int q = 0; q < 4; ++q) {
      int nt = w + (q << 2);
      if (nt <= 12) {
        size_t boff = (cb + nt * 16 + n16) * ND + dk * 32 + g * 8;
        bf16x8 Bh = *(const bf16x8*)(cTh + boff);
        bf16x8 Bl = *(const bf16x8*)(cTl + boff);
        accG[q] = mfma16(Ah, Bh, accG[q]);
        accG[q] = mfma16(Ah, Bl, accG[q]);
        accG[q] = mfma16(Al, Bh, accG[q]);
      }
    }
  }
#pragma unroll
  for (int q = 0; q < 4; ++q) {
    int nt = w + (q << 2);
    if (nt <= 13) {
#pragma unroll
      for (int r = 0; r < 4; ++r) {
        int s = st * 16 + g * 4 + r;
        int col = nt * 16 + n16;
        float v = (nt <= 12) ? accG[q][r] : 0.f;
        __bf16 hi = (__bf16)v;
        __bf16 lo = (__bf16)(v - (float)hi);
        size_t o = ((size_t)j * 208 + s) * 224 + col;
        Ghp[o] = hi;
        Glp[o] = lo;
      }
    }
  }
}

// -------------------- per-pair fused local loss (MFMA) --------------------
__global__ __launch_bounds__(256, 2) void pair_kernel(
    const __bf16* __restrict__ txh, const __bf16* __restrict__ txl,
    const __bf16* __restrict__ cTh, const __bf16* __restrict__ cTl,
    const __bf16* __restrict__ Ghp, const __bf16* __restrict__ Glp,
    const float* __restrict__ n1ws, const int* __restrict__ lenws,
    float* __restrict__ simws) {
  const int t = threadIdx.x;
  const int bid = blockIdx.x;
  const int j = bid >> 5, i = bid & 31;
  const int len = lenws[i];
  const int nlt = (len + 15) >> 4;
  const int lane = t & 63, w = t >> 6;
  const int g = lane >> 4, n16 = lane & 15;
  const int nst = (w == 0) ? 4 : 3;

  __shared__ __align__(16) __bf16 e2f[7 * 5 * 64 * 8];       // 35840 B, B-frag layout
  __shared__ __align__(16) __bf16 b1[2][5][2][64][8];        // 20480 B, dbuf B staging
  __shared__ float w12s[80], z2s[80], n2s[80];

  // zero-init
  for (int idx = t; idx < 2240; idx += 256) ((uint4*)e2f)[idx] = make_uint4(0, 0, 0, 0);
  if (t < 80) { w12s[t] = 0.f; z2s[t] = 0.f; n2s[t] = 0.f; }

  const f32x4 z4 = {0.f, 0.f, 0.f, 0.f};
  f32x4 acc[4][5];
#pragma unroll
  for (int q = 0; q < 4; ++q)
#pragma unroll
    for (int lt = 0; lt < 5; ++lt) acc[q][lt] = z4;

  const size_t arow = (size_t)j * 208;
  const int ntask = nlt << 7;

  // ---- prologue: stage dk=0 B tiles, load dk=0 A frags ----
#pragma unroll
  for (int k = 0; k < 3; ++k) {
    int tau = t + (k << 8);
    if (tau < ntask) {
      int lt = tau >> 7, pl = (tau >> 6) & 1, ln = tau & 63;
      int l = (lt << 4) + (ln & 15), gg = (ln >> 4) & 3;
      const __bf16* src = (pl ? txl : txh) + ((size_t)i * 80 + l) * ND + gg * 8;
      *(uint4*)&b1[0][lt][pl][ln][0] = *(const uint4*)src;
    }
  }
  bf16x8 Ah[4], Al[4];
#pragma unroll
  for (int q = 0; q < 4; ++q) {
    if (q < nst) {
      int S = w + (q << 2);
      size_t off = (arow + S * 16 + n16) * ND + g * 8;
      Ah[q] = *(const bf16x8*)(cTh + off);
      Al[q] = *(const bf16x8*)(cTl + off);
    }
  }
  __syncthreads();

  // ---- phase 1: logits = ctx^T tl via split-bf16 MFMA ----
#pragma unroll 1
  for (int dk = 0; dk < 24; ++dk) {
    const int cur = dk & 1;
    bf16x8 AhN[4], AlN[4];
    uint4 sreg[3];
    if (dk < 23) {
#pragma unroll
      for (int q = 0; q < 4; ++q) {
        if (q < nst) {
          int S = w + (q << 2);
          size_t off = (arow + S * 16 + n16) * ND + (dk + 1) * 32 + g * 8;
          AhN[q] = *(const bf16x8*)(cTh + off);
          AlN[q] = *(const bf16x8*)(cTl + off);
        }
      }
#pragma unroll
      for (int k = 0; k < 3; ++k) {
        int tau = t + (k << 8);
        if (tau < ntask) {
          int lt = tau >> 7, pl = (tau >> 6) & 1, ln = tau & 63;
          int l = (lt << 4) + (ln & 15), gg = (ln >> 4) & 3;
          sreg[k] = *(const uint4*)((pl ? txl : txh) + ((size_t)i * 80 + l) * ND + (dk + 1) * 32 + gg * 8);
        }
      }
    }
#pragma unroll
    for (int lt = 0; lt < 5; ++lt) {
      if (lt < nlt) {
        bf16x8 Bh = *(const bf16x8*)&b1[cur][lt][0][lane][0];
        bf16x8 Bl = *(const bf16x8*)&b1[cur][lt][1][lane][0];
#pragma unroll
        for (int q = 0; q < 4; ++q) {
          if (q < nst) {
            acc[q][lt] = mfma16(Ah[q], Bh, acc[q][lt]);
            acc[q][lt] = mfma16(Ah[q], Bl, acc[q][lt]);
            acc[q][lt] = mfma16(Al[q], Bh, acc[q][lt]);
          }
        }
      }
    }
    if (dk < 23) {
#pragma unroll
      for (int k = 0; k < 3; ++k) {
        int tau = t + (k << 8);
        if (tau < ntask) {
          int lt = tau >> 7, pl = (tau >> 6) & 1, ln = tau & 63;
          *(uint4*)&b1[cur ^ 1][lt][pl][ln][0] = sreg[k];
        }
      }
#pragma unroll
      for (int q = 0; q < 4; ++q) {
        if (q < nst) { Ah[q] = AhN[q]; Al[q] = AlN[q]; }
      }
    }
    __syncthreads();
  }

  // ---- phase 2: register-resident softmax over l, e2 = exp(4*a1), fold w12/Z2 ----
  float w12loc[5], z2loc[5];
#pragma unroll
  for (int lt = 0; lt < 5; ++lt) { w12loc[lt] = 0.f; z2loc[lt] = 0.f; }
#pragma unroll
  for (int q = 0; q < 4; ++q) {
    if (q < nst) {
      int S = w + (q << 2);
#pragma unroll
      for (int r = 0; r < 4; ++r) {
        int s = S * 16 + g * 4 + r;
        bool srow = (s < NS);
        float m = -1e30f;
#pragma unroll
        for (int lt = 0; lt < 5; ++lt) {
          if (lt < nlt) {
            bool vl = (lt * 16 + n16) < len;
            float v = acc[q][lt][r];
            if (vl) m = fmaxf(m, v);
          }
        }
        m = fmaxf(m, __shfl_xor(m, 1));
        m = fmaxf(m, __shfl_xor(m, 2));
        m = fmaxf(m, __shfl_xor(m, 4));
        m = fmaxf(m, __shfl_xor(m, 8));
        float z = 0.f;
        float ev[5];
#pragma unroll
        for (int lt = 0; lt < 5; ++lt) {
          float e = 0.f;
          if (lt < nlt) {
            bool vl = (lt * 16 + n16) < len;
            float v = acc[q][lt][r];
            if (vl) e = __expf(v - m);
          }
          ev[lt] = e;
          z += e;
        }
        z += __shfl_xor(z, 1);
        z += __shfl_xor(z, 2);
        z += __shfl_xor(z, 4);
        z += __shfl_xor(z, 8);
        float inv = 4.0f / z;
#pragma unroll
        for (int lt = 0; lt < 5; ++lt) {
          if (lt < nlt) {
            bool vl = (lt * 16 + n16) < len;
            if (vl && srow) {
              float e2 = __expf(ev[lt] * inv);
              float v = acc[q][lt][r];
              w12loc[lt] += e2 * v;
              z2loc[lt] += e2;
              int kt = s >> 5, kk = s & 31;
              e2f[(((kt * 5) + lt) * 64 + (n16 + ((kk >> 3) << 4))) * 8 + (kk & 7)] = (__bf16)e2;
            }
          }
        }
      }
    }
  }
#pragma unroll
  for (int lt = 0; lt < 5; ++lt) {
    w12loc[lt] += __shfl_xor(w12loc[lt], 16);
    w12loc[lt] += __shfl_xor(w12loc[lt], 32);
    z2loc[lt] += __shfl_xor(z2loc[lt], 16);
    z2loc[lt] += __shfl_xor(z2loc[lt], 32);
  }
  if (lane < 16) {
#pragma unroll
    for (int lt = 0; lt < 5; ++lt) {
      if (lt < nlt) {
        atomicAdd(&w12s[lt * 16 + lane], w12loc[lt]);
        atomicAdd(&z2s[lt * 16 + lane], z2loc[lt]);
      }
    }
  }
  __syncthreads();

  // ---- phase 3: n2 = e2^T G e2 via MFMA (V = G*e2, fold n2) ----
  float n2loc[5];
#pragma unroll
  for (int lt = 0; lt < 5; ++lt) n2loc[lt] = 0.f;
  const size_t gb = (size_t)j * 208;
#pragma unroll
  for (int q = 0; q < 4; ++q) {
    if (q < nst) {
      int S = w + (q << 2);
      f32x4 a2[5];
#pragma unroll
      for (int lt = 0; lt < 5; ++lt) a2[lt] = z4;
#pragma unroll
      for (int kt = 0; kt < 7; ++kt) {
        size_t goff = (gb + S * 16 + n16) * 224 + kt * 32 + g * 8;
        bf16x8 GAh = *(const bf16x8*)(Ghp + goff);
        bf16x8 GAl = *(const bf16x8*)(Glp + goff);
#pragma unroll
        for (int lt = 0; lt < 5; ++lt) {
          if (lt < nlt) {
            bf16x8 Bv = *(const bf16x8*)&e2f[(((kt * 5) + lt) * 64 + lane) * 8];
            a2[lt] = mfma16(GAh, Bv, a2[lt]);
            a2[lt] = mfma16(GAl, Bv, a2[lt]);
          }
        }
      }
#pragma unroll
      for (int lt = 0; lt < 5; ++lt) {
        if (lt < nlt) {
#pragma unroll
          for (int r = 0; r < 4; ++r) {
            int s = S * 16 + g * 4 + r;
            int kt = s >> 5, kk = s & 31;
            float e2v = (float)e2f[(((kt * 5) + lt) * 64 + (n16 + ((kk >> 3) << 4))) * 8 + (kk & 7)];
            n2loc[lt] += e2v * a2[lt][r];
          }
        }
      }
    }
  }
#pragma unroll
  for (int lt = 0; lt < 5; ++lt) {
    n2loc[lt] += __shfl_xor(n2loc[lt], 16);
    n2loc[lt] += __shfl_xor(n2loc[lt], 32);
  }
  if (lane < 16) {
#pragma unroll
    for (int lt = 0; lt < 5; ++lt) {
      if (lt < nlt) atomicAdd(&n2s[lt * 16 + lane], n2loc[lt]);
    }
  }
  __syncthreads();

  // ---- epilogue: cosine + log-sum-exp ----
  if (t < len) {
    float z2 = z2s[t];
    float w12v = w12s[t] / z2;
    float n2v = sqrtf(n2s[t]) / z2;
    float n1v = n1ws[i * 80 + t];
    float cosv = w12v / fmaxf(n1v * n2v, 1e-8f);
    w12s[t] = __expf(5.0f * cosv);
  }
  __syncthreads();
  if (t == 0) {
    float sum = 0.f;
    for (int l = 0; l < len; ++l) sum += w12s[l];
    simws[i * NB + j] = __logf(sum);
  }
}

// -------------------- final cross-entropies --------------------
__global__ void loss_kernel(const float* __restrict__ gscw,
                            const float* __restrict__ simws,
                            float* __restrict__ out) {
  const int t = threadIdx.x;
  __shared__ float gs[NB][NB];
  __shared__ float sl[NB][NB];
  __shared__ float parts[4][NB];
  {
    float4 gv = ((const float4*)gscw)[t];
    ((float4*)gs)[t] = gv;
    float4 v = ((const float4*)simws)[t];
    int ii = t >> 3;
    int j0 = (t & 7) * 4;
    sl[j0 + 0][ii] = v.x * 10.0f;
    sl[j0 + 1][ii] = v.y * 10.0f;
    sl[j0 + 2][ii] = v.z * 10.0f;
    sl[j0 + 3][ii] = v.w * 10.0f;
  }
  __syncthreads();
  if (t < NB) {
    float m, z;
    m = -1e30f;
    for (int c = 0; c < NB; ++c) m = fmaxf(m, gs[t][c]);
    z = 0.f;
    for (int c = 0; c < NB; ++c) z += __expf(gs[t][c] - m);
    parts[0][t] = m + __logf(z) - gs[t][t];

    m = -1e30f;
    for (int c = 0; c < NB; ++c) m = fmaxf(m, gs[c][t]);
    z = 0.f;
    for (int c = 0; c < NB; ++c) z += __expf(gs[c][t] - m);
    parts[1][t] = m + __logf(z) - gs[t][t];

    m = -1e30f;
    for (int c = 0; c < NB; ++c) m = fmaxf(m, sl[t][c]);
    z = 0.f;
    for (int c = 0; c < NB; ++c) z += __expf(sl[t][c] - m);
    parts[2][t] = m + __logf(z) - sl[t][t];

    m = -1e30f;
    for (int c = 0; c < NB; ++c) m = fmaxf(m, sl[c][t]);
    z = 0.f;
    for (int c = 0; c < NB; ++c) z += __expf(sl[c][t] - m);
    parts[3][t] = m + __logf(z) - sl[t][t];
  }
  __syncthreads();
  if (t == 0) {
    float s0 = 0.f, s1 = 0.f, s2 = 0.f, s3 = 0.f;
    for (int r = 0; r < NB; ++r) {
      s0 += parts[0][r]; s1 += parts[1][r];
      s2 += parts[2][r]; s3 += parts[3][r];
    }
    out[0] = 0.5f * (s0 + s1) / 32.0f + 0.5f * (s2 + s3) / 32.0f;
  }
}

extern "C" void kernel_launch(void* const* d_in, const int* in_sizes, int n_in,
                              void* d_out, int out_size, void* d_ws, size_t ws_size,
                              hipStream_t stream) {
  (void)in_sizes; (void)n_in; (void)out_size; (void)ws_size;
  const float* img_global  = (const float*)d_in[0];
  const float* img_local   = (const float*)d_in[1];
  const float* text_global = (const float*)d_in[2];
  const float* text_local  = (const float*)d_in[3];
  const int*   amask       = (const int*)d_in[4];

  __bf16* txh = (__bf16*)d_ws;
  __bf16* txl = txh + (size_t)32 * 80 * ND;
  __bf16* cTh = txl + (size_t)32 * 80 * ND;
  __bf16* cTl = cTh + (size_t)32 * 208 * ND;
  __bf16* Ghp = cTl + (size_t)32 * 208 * ND;
  __bf16* Glp = Ghp + (size_t)32 * 208 * 224;
  float* fsm  = (float*)(Glp + (size_t)32 * 208 * 224);
  float* n1ws  = fsm;
  float* simws = fsm + 2560;
  float* gscw  = fsm + 3584;
  float* invni = fsm + 4608;
  float* invnt = fsm + 4640;
  int*   lenws = (int*)(fsm + 4672);

  prep_kernel<<<32, 256, 0, stream>>>(img_global, text_global, text_local, amask,
                                      n1ws, lenws, invni, invnt);
  tx_kernel<<<960, 256, 0, stream>>>(text_local, txh, txl);
  trans_kernel<<<384, 256, 0, stream>>>(img_local, cTh, cTl);
  gram_kernel<<<416, 256, 0, stream>>>(cTh, cTl, Ghp, Glp);
  gsc_kernel<<<32, 256, 0, stream>>>(img_global, text_global, invni, invnt, gscw);
  pair_kernel<<<1024, 256, 0, stream>>>(txh, txl, cTh, cTl, Ghp, Glp, n1ws, lenws, simws);
  loss_kernel<<<1, 256, 0, stream>>>(gscw, simws, (float*)d_out);
}